// Round 1
// baseline (566.942 us; speedup 1.0000x reference)
//
#include <hip/hip_runtime.h>
#include <hip/hip_bf16.h>

typedef __bf16 bf16x8 __attribute__((ext_vector_type(8)));
typedef float floatx4 __attribute__((ext_vector_type(4)));

#define FP8_MAX 448.0f
#define QEPS 1e-8f

// async 16B global -> LDS (dest must be wave-uniform base + lane*16)
#define GLLDS16(gptr, lptr)                                                          \
  __builtin_amdgcn_global_load_lds((const __attribute__((address_space(1))) void*)(gptr), \
                                   (__attribute__((address_space(3))) void*)(lptr), 16, 0, 0)

// ---------------------------------------------------------------------------
// fp8-e4m3 groupwise pseudo-quantize (group=32 along last dim) -> bf16 dequant
// 8 lanes cooperate per group; each lane handles 4 consecutive floats.
// ---------------------------------------------------------------------------
__global__ __launch_bounds__(256) void quant_dq_kernel(
    const float* __restrict__ src, __hip_bfloat16* __restrict__ dst, long long n)
{
    long long t = (long long)blockIdx.x * blockDim.x + threadIdx.x;
    long long base = t * 4;
    if (base >= n) return;

    const float4 v = *(const float4*)(src + base);
    float am = fmaxf(fmaxf(fabsf(v.x), fabsf(v.y)), fmaxf(fabsf(v.z), fabsf(v.w)));
    // reduce amax over the 8 lanes covering one 32-element group
    am = fmaxf(am, __shfl_xor(am, 1));
    am = fmaxf(am, __shfl_xor(am, 2));
    am = fmaxf(am, __shfl_xor(am, 4));
    const float scale = fmaxf(am, QEPS) / FP8_MAX;

    // q = fp8(x/scale)  (HW cvt on gfx950 is OCP e4m3fn, RNE — matches ml_dtypes)
    int p0 = __builtin_amdgcn_cvt_pk_fp8_f32(v.x / scale, v.y / scale, 0, false);
    int p1 = __builtin_amdgcn_cvt_pk_fp8_f32(v.z / scale, v.w / scale, 0, false);
    float r0 = __builtin_amdgcn_cvt_f32_fp8(p0, 0) * scale;
    float r1 = __builtin_amdgcn_cvt_f32_fp8(p0, 1) * scale;
    float r2 = __builtin_amdgcn_cvt_f32_fp8(p1, 0) * scale;
    float r3 = __builtin_amdgcn_cvt_f32_fp8(p1, 1) * scale;

    alignas(8) __hip_bfloat16 hb[4] = {
        __float2bfloat16(r0), __float2bfloat16(r1),
        __float2bfloat16(r2), __float2bfloat16(r3)};
    *(ushort4*)(dst + base) = *(const ushort4*)hb;
}

// ---------------------------------------------------------------------------
// bf16 NT GEMM + bias:  C[m][n] = sum_k A[m][k]*B[n][k] + bias[n]
// m97 structure: 128x128 block, BK=32, 4 waves (2x2), 16x16x32 MFMA, 4x4/wave,
// global_load_lds width-16 staging, 2-barrier K-loop.
// ---------------------------------------------------------------------------
__global__ __launch_bounds__(256, 2) void gemm_bias_kernel(
    const __hip_bfloat16* __restrict__ A,   // [M][K]
    const __hip_bfloat16* __restrict__ B,   // [N][K]
    const float* __restrict__ bias,         // [N]
    float* __restrict__ C,                  // [M][N]
    int M, int N, int K)
{
    __shared__ __attribute__((aligned(16))) __hip_bfloat16 As[128 * 32];
    __shared__ __attribute__((aligned(16))) __hip_bfloat16 Bs[128 * 32];

    const int tid  = threadIdx.x;
    const int lane = tid & 63;
    const int wave = tid >> 6;
    const int wr   = (wave >> 1) * 64;   // wave row offset in block tile
    const int wc   = (wave & 1) * 64;    // wave col offset in block tile

    const long bm = (long)blockIdx.y * 128;
    const long bn = (long)blockIdx.x * 128;

    // staging: thread covers 8 bf16 (16B); LDS contiguous in lane order
    const int srow = tid >> 2;           // 0..63
    const int scol = (tid & 3) * 8;      // 0,8,16,24

    const __hip_bfloat16* gA0 = A + (bm + srow) * (long)K + scol;
    const __hip_bfloat16* gA1 = A + (bm + 64 + srow) * (long)K + scol;
    const __hip_bfloat16* gB0 = B + (bn + srow) * (long)K + scol;
    const __hip_bfloat16* gB1 = B + (bn + 64 + srow) * (long)K + scol;

    __hip_bfloat16* lA0 = As + tid * 8;
    __hip_bfloat16* lA1 = As + 2048 + tid * 8;
    __hip_bfloat16* lB0 = Bs + tid * 8;
    __hip_bfloat16* lB1 = Bs + 2048 + tid * 8;

    floatx4 acc[4][4];
#pragma unroll
    for (int i = 0; i < 4; ++i)
#pragma unroll
        for (int j = 0; j < 4; ++j)
            acc[i][j] = (floatx4){0.f, 0.f, 0.f, 0.f};

    const int fr = lane & 15;            // A row / B col within 16-tile
    const int fk = (lane >> 4) * 8;      // k offset within 32

    for (int k0 = 0; k0 < K; k0 += 32) {
        GLLDS16(gA0 + k0, lA0);
        GLLDS16(gA1 + k0, lA1);
        GLLDS16(gB0 + k0, lB0);
        GLLDS16(gB1 + k0, lB1);
        __syncthreads();   // compiler inserts vmcnt(0) drain before s_barrier

        bf16x8 af[4], bfv[4];
#pragma unroll
        for (int i = 0; i < 4; ++i)
            af[i] = *(const bf16x8*)(As + (wr + i * 16 + fr) * 32 + fk);
#pragma unroll
        for (int j = 0; j < 4; ++j)
            bfv[j] = *(const bf16x8*)(Bs + (wc + j * 16 + fr) * 32 + fk);

#pragma unroll
        for (int i = 0; i < 4; ++i)
#pragma unroll
            for (int j = 0; j < 4; ++j)
                acc[i][j] = __builtin_amdgcn_mfma_f32_16x16x32_bf16(af[i], bfv[j], acc[i][j], 0, 0, 0);
        __syncthreads();
    }

    // epilogue: C/D layout col=lane&15, row=(lane>>4)*4+reg  [m89/m91]
    const int rq = (lane >> 4) * 4;
#pragma unroll
    for (int j = 0; j < 4; ++j) {
        const long gc = bn + wc + j * 16 + fr;
        const float bj = bias[gc];
#pragma unroll
        for (int i = 0; i < 4; ++i) {
            const long gr = bm + wr + i * 16 + rq;
            float* cp = C + gr * (long)N + gc;
#pragma unroll
            for (int r = 0; r < 4; ++r)
                cp[(long)r * N] = acc[i][j][r] + bj;
        }
    }
}

extern "C" void kernel_launch(void* const* d_in, const int* in_sizes, int n_in,
                              void* d_out, int out_size, void* d_ws, size_t ws_size,
                              hipStream_t stream) {
    const float* x    = (const float*)d_in[0];   // [B,S,K] fp32
    const float* W    = (const float*)d_in[1];   // [N,K]   fp32
    const float* bias = (const float*)d_in[2];   // [N]     fp32
    float* out = (float*)d_out;

    const long long nx = in_sizes[0];
    const long long nw = in_sizes[1];
    const int N = in_sizes[2];
    const int K = (int)(nw / N);
    const int M = (int)(nx / K);

    __hip_bfloat16* xq = (__hip_bfloat16*)d_ws;
    __hip_bfloat16* wq = xq + nx;

    // quantize+dequant x and W to bf16 in workspace
    {
        long long tx = nx / 4;
        int blocks = (int)((tx + 255) / 256);
        quant_dq_kernel<<<blocks, 256, 0, stream>>>(x, xq, nx);
    }
    {
        long long tw = nw / 4;
        int blocks = (int)((tw + 255) / 256);
        quant_dq_kernel<<<blocks, 256, 0, stream>>>(W, wq, nw);
    }

    // GEMM + bias
    dim3 grid(N / 128, M / 128);
    gemm_bias_kernel<<<grid, 256, 0, stream>>>(xq, wq, bias, out, M, N, K);
}

// Round 2
// 556.746 us; speedup vs baseline: 1.0183x; 1.0183x over previous
//
#include <hip/hip_runtime.h>
#include <hip/hip_bf16.h>

typedef __bf16 bf16x8 __attribute__((ext_vector_type(8)));
typedef float floatx4 __attribute__((ext_vector_type(4)));
typedef unsigned short ushortx8 __attribute__((ext_vector_type(8)));

#define FP8_MAX 448.0f
#define QEPS 1e-8f

// async 16B global -> LDS (dest must be wave-uniform base + lane*16)
#define GLLDS16(gptr, lptr)                                                          \
  __builtin_amdgcn_global_load_lds((const __attribute__((address_space(1))) void*)(gptr), \
                                   (__attribute__((address_space(3))) void*)(lptr), 16, 0, 0)

// ---------------------------------------------------------------------------
// fp8-e4m3 groupwise pseudo-quantize (group=32 along last dim) -> bf16 dequant
// 4 lanes cooperate per group; each lane handles 8 consecutive floats.
// 2 shuffles for amax (was 3), 16B coalesced stores (was 8B).
// Division is exact fp32 (bit-identical to reference x/scale before fp8 cvt).
// ---------------------------------------------------------------------------
__global__ __launch_bounds__(256) void quant_dq_kernel(
    const float* __restrict__ src, __hip_bfloat16* __restrict__ dst, long long n)
{
    long long t = (long long)blockIdx.x * blockDim.x + threadIdx.x;
    long long base = t * 8;
    if (base >= n) return;

    const float4 v0 = *(const float4*)(src + base);
    const float4 v1 = *(const float4*)(src + base + 4);

    float am = fmaxf(
        fmaxf(fmaxf(fabsf(v0.x), fabsf(v0.y)), fmaxf(fabsf(v0.z), fabsf(v0.w))),
        fmaxf(fmaxf(fabsf(v1.x), fabsf(v1.y)), fmaxf(fabsf(v1.z), fabsf(v1.w))));
    // reduce amax over the 4 lanes covering one 32-element group
    am = fmaxf(am, __shfl_xor(am, 1));
    am = fmaxf(am, __shfl_xor(am, 2));
    const float scale = fmaxf(am, QEPS) / FP8_MAX;

    // q = fp8(x/scale)  (HW cvt on gfx950 is OCP e4m3fn, RNE — matches ml_dtypes)
    int p0 = __builtin_amdgcn_cvt_pk_fp8_f32(v0.x / scale, v0.y / scale, 0, false);
    int p1 = __builtin_amdgcn_cvt_pk_fp8_f32(v0.z / scale, v0.w / scale, 0, false);
    int p2 = __builtin_amdgcn_cvt_pk_fp8_f32(v1.x / scale, v1.y / scale, 0, false);
    int p3 = __builtin_amdgcn_cvt_pk_fp8_f32(v1.z / scale, v1.w / scale, 0, false);

    float r0 = __builtin_amdgcn_cvt_f32_fp8(p0, 0) * scale;
    float r1 = __builtin_amdgcn_cvt_f32_fp8(p0, 1) * scale;
    float r2 = __builtin_amdgcn_cvt_f32_fp8(p1, 0) * scale;
    float r3 = __builtin_amdgcn_cvt_f32_fp8(p1, 1) * scale;
    float r4 = __builtin_amdgcn_cvt_f32_fp8(p2, 0) * scale;
    float r5 = __builtin_amdgcn_cvt_f32_fp8(p2, 1) * scale;
    float r6 = __builtin_amdgcn_cvt_f32_fp8(p3, 0) * scale;
    float r7 = __builtin_amdgcn_cvt_f32_fp8(p3, 1) * scale;

    alignas(16) __hip_bfloat16 hb[8] = {
        __float2bfloat16(r0), __float2bfloat16(r1),
        __float2bfloat16(r2), __float2bfloat16(r3),
        __float2bfloat16(r4), __float2bfloat16(r5),
        __float2bfloat16(r6), __float2bfloat16(r7)};
    *(ushortx8*)(dst + base) = *(const ushortx8*)hb;
}

// ---------------------------------------------------------------------------
// bf16 NT GEMM + bias:  C[m][n] = sum_k A[m][k]*B[n][k] + bias[n]
// m97 structure: 128x128 block, BK=32, 4 waves (2x2), 16x16x32 MFMA, 4x4/wave,
// global_load_lds width-16 staging, 2-barrier K-loop.  (unchanged from R1;
// measured 843 TF = m97 plateau)
// ---------------------------------------------------------------------------
__global__ __launch_bounds__(256, 2) void gemm_bias_kernel(
    const __hip_bfloat16* __restrict__ A,   // [M][K]
    const __hip_bfloat16* __restrict__ B,   // [N][K]
    const float* __restrict__ bias,         // [N]
    float* __restrict__ C,                  // [M][N]
    int M, int N, int K)
{
    __shared__ __attribute__((aligned(16))) __hip_bfloat16 As[128 * 32];
    __shared__ __attribute__((aligned(16))) __hip_bfloat16 Bs[128 * 32];

    const int tid  = threadIdx.x;
    const int lane = tid & 63;
    const int wave = tid >> 6;
    const int wr   = (wave >> 1) * 64;   // wave row offset in block tile
    const int wc   = (wave & 1) * 64;    // wave col offset in block tile

    const long bm = (long)blockIdx.y * 128;
    const long bn = (long)blockIdx.x * 128;

    // staging: thread covers 8 bf16 (16B); LDS contiguous in lane order
    const int srow = tid >> 2;           // 0..63
    const int scol = (tid & 3) * 8;      // 0,8,16,24

    const __hip_bfloat16* gA0 = A + (bm + srow) * (long)K + scol;
    const __hip_bfloat16* gA1 = A + (bm + 64 + srow) * (long)K + scol;
    const __hip_bfloat16* gB0 = B + (bn + srow) * (long)K + scol;
    const __hip_bfloat16* gB1 = B + (bn + 64 + srow) * (long)K + scol;

    __hip_bfloat16* lA0 = As + tid * 8;
    __hip_bfloat16* lA1 = As + 2048 + tid * 8;
    __hip_bfloat16* lB0 = Bs + tid * 8;
    __hip_bfloat16* lB1 = Bs + 2048 + tid * 8;

    floatx4 acc[4][4];
#pragma unroll
    for (int i = 0; i < 4; ++i)
#pragma unroll
        for (int j = 0; j < 4; ++j)
            acc[i][j] = (floatx4){0.f, 0.f, 0.f, 0.f};

    const int fr = lane & 15;            // A row / B col within 16-tile
    const int fk = (lane >> 4) * 8;      // k offset within 32

    for (int k0 = 0; k0 < K; k0 += 32) {
        GLLDS16(gA0 + k0, lA0);
        GLLDS16(gA1 + k0, lA1);
        GLLDS16(gB0 + k0, lB0);
        GLLDS16(gB1 + k0, lB1);
        __syncthreads();

        bf16x8 af[4], bfv[4];
#pragma unroll
        for (int i = 0; i < 4; ++i)
            af[i] = *(const bf16x8*)(As + (wr + i * 16 + fr) * 32 + fk);
#pragma unroll
        for (int j = 0; j < 4; ++j)
            bfv[j] = *(const bf16x8*)(Bs + (wc + j * 16 + fr) * 32 + fk);

#pragma unroll
        for (int i = 0; i < 4; ++i)
#pragma unroll
            for (int j = 0; j < 4; ++j)
                acc[i][j] = __builtin_amdgcn_mfma_f32_16x16x32_bf16(af[i], bfv[j], acc[i][j], 0, 0, 0);
        __syncthreads();
    }

    // epilogue: C/D layout col=lane&15, row=(lane>>4)*4+reg  [m89/m91]
    const int rq = (lane >> 4) * 4;
#pragma unroll
    for (int j = 0; j < 4; ++j) {
        const long gc = bn + wc + j * 16 + fr;
        const float bj = bias[gc];
#pragma unroll
        for (int i = 0; i < 4; ++i) {
            const long gr = bm + wr + i * 16 + rq;
            float* cp = C + gr * (long)N + gc;
#pragma unroll
            for (int r = 0; r < 4; ++r)
                cp[(long)r * N] = acc[i][j][r] + bj;
        }
    }
}

extern "C" void kernel_launch(void* const* d_in, const int* in_sizes, int n_in,
                              void* d_out, int out_size, void* d_ws, size_t ws_size,
                              hipStream_t stream) {
    const float* x    = (const float*)d_in[0];   // [B,S,K] fp32
    const float* W    = (const float*)d_in[1];   // [N,K]   fp32
    const float* bias = (const float*)d_in[2];   // [N]     fp32
    float* out = (float*)d_out;

    const long long nx = in_sizes[0];
    const long long nw = in_sizes[1];
    const int N = in_sizes[2];
    const int K = (int)(nw / N);
    const int M = (int)(nx / K);

    __hip_bfloat16* xq = (__hip_bfloat16*)d_ws;
    __hip_bfloat16* wq = xq + nx;

    // quantize+dequant x and W to bf16 in workspace
    {
        long long tx = nx / 8;
        int blocks = (int)((tx + 255) / 256);
        quant_dq_kernel<<<blocks, 256, 0, stream>>>(x, xq, nx);
    }
    {
        long long tw = nw / 8;
        int blocks = (int)((tw + 255) / 256);
        quant_dq_kernel<<<blocks, 256, 0, stream>>>(W, wq, nw);
    }

    // GEMM + bias
    dim3 grid(N / 128, M / 128);
    gemm_bias_kernel<<<grid, 256, 0, stream>>>(xq, wq, bias, out, M, N, K);
}

// Round 3
// 506.253 us; speedup vs baseline: 1.1199x; 1.0997x over previous
//
#include <hip/hip_runtime.h>
#include <hip/hip_bf16.h>

typedef __bf16 bf16x8 __attribute__((ext_vector_type(8)));
typedef float floatx4 __attribute__((ext_vector_type(4)));
typedef unsigned short ushortx8 __attribute__((ext_vector_type(8)));

#define FP8_MAX 448.0f
#define QEPS 1e-8f

// async 16B global -> LDS (dest must be wave-uniform base + lane*16)
#define GLLDS16(gptr, lptr)                                                          \
  __builtin_amdgcn_global_load_lds((const __attribute__((address_space(1))) void*)(gptr), \
                                   (__attribute__((address_space(3))) void*)(lptr), 16, 0, 0)

// ---------------------------------------------------------------------------
// fp8-e4m3 groupwise pseudo-quantize (group=32 along last dim) -> bf16 dequant
// 4 lanes per group, 8 elems/lane, exact fp32 division (matches reference).
// ---------------------------------------------------------------------------
__global__ __launch_bounds__(256) void quant_dq_kernel(
    const float* __restrict__ src, __hip_bfloat16* __restrict__ dst, long long n)
{
    long long t = (long long)blockIdx.x * blockDim.x + threadIdx.x;
    long long base = t * 8;
    if (base >= n) return;

    const float4 v0 = *(const float4*)(src + base);
    const float4 v1 = *(const float4*)(src + base + 4);

    float am = fmaxf(
        fmaxf(fmaxf(fabsf(v0.x), fabsf(v0.y)), fmaxf(fabsf(v0.z), fabsf(v0.w))),
        fmaxf(fmaxf(fabsf(v1.x), fabsf(v1.y)), fmaxf(fabsf(v1.z), fabsf(v1.w))));
    am = fmaxf(am, __shfl_xor(am, 1));
    am = fmaxf(am, __shfl_xor(am, 2));
    const float scale = fmaxf(am, QEPS) / FP8_MAX;

    int p0 = __builtin_amdgcn_cvt_pk_fp8_f32(v0.x / scale, v0.y / scale, 0, false);
    int p1 = __builtin_amdgcn_cvt_pk_fp8_f32(v0.z / scale, v0.w / scale, 0, false);
    int p2 = __builtin_amdgcn_cvt_pk_fp8_f32(v1.x / scale, v1.y / scale, 0, false);
    int p3 = __builtin_amdgcn_cvt_pk_fp8_f32(v1.z / scale, v1.w / scale, 0, false);

    float r0 = __builtin_amdgcn_cvt_f32_fp8(p0, 0) * scale;
    float r1 = __builtin_amdgcn_cvt_f32_fp8(p0, 1) * scale;
    float r2 = __builtin_amdgcn_cvt_f32_fp8(p1, 0) * scale;
    float r3 = __builtin_amdgcn_cvt_f32_fp8(p1, 1) * scale;
    float r4 = __builtin_amdgcn_cvt_f32_fp8(p2, 0) * scale;
    float r5 = __builtin_amdgcn_cvt_f32_fp8(p2, 1) * scale;
    float r6 = __builtin_amdgcn_cvt_f32_fp8(p3, 0) * scale;
    float r7 = __builtin_amdgcn_cvt_f32_fp8(p3, 1) * scale;

    alignas(16) __hip_bfloat16 hb[8] = {
        __float2bfloat16(r0), __float2bfloat16(r1),
        __float2bfloat16(r2), __float2bfloat16(r3),
        __float2bfloat16(r4), __float2bfloat16(r5),
        __float2bfloat16(r6), __float2bfloat16(r7)};
    *(ushortx8*)(dst + base) = *(const ushortx8*)hb;
}

// ---------------------------------------------------------------------------
// bf16 NT GEMM + bias:  C[m][n] = sum_k A[m][k]*B[n][k] + bias[n]
// 128x128 block, BK=64 (32 MFMA per barrier pair), 4 waves (2x2), 16x16x32
// MFMA 4x4/wave, global_load_lds width-16 staging, XOR-swizzled LDS chunks
// to kill frag-read bank conflicts (swizzle applied to GLOBAL source chunk,
// so lane->LDS mapping stays contiguous as global_load_lds requires).
// LDS layout: row-major [128][64], chunk p (8 elems) of row r holds global
// chunk p ^ (r & 7).
// ---------------------------------------------------------------------------
__global__ __launch_bounds__(256, 2) void gemm_bias_kernel(
    const __hip_bfloat16* __restrict__ A,   // [M][K]
    const __hip_bfloat16* __restrict__ B,   // [N][K]
    const float* __restrict__ bias,         // [N]
    float* __restrict__ C,                  // [M][N]
    int M, int N, int K)
{
    __shared__ __attribute__((aligned(16))) __hip_bfloat16 As[128 * 64];
    __shared__ __attribute__((aligned(16))) __hip_bfloat16 Bs[128 * 64];

    const int tid  = threadIdx.x;
    const int lane = tid & 63;
    const int wave = tid >> 6;
    const int wr   = (wave >> 1) * 64;   // wave row offset in block tile
    const int wc   = (wave & 1) * 64;    // wave col offset in block tile

    const long bm = (long)blockIdx.y * 128;
    const long bn = (long)blockIdx.x * 128;

    // staging: 8 chunks of 8 bf16 per 64-col row; 8 threads/row; 32 rows/call
    const int srow = tid >> 3;                       // 0..31
    const int scg  = (tid & 7) ^ (srow & 7);         // swizzled global chunk

    const __hip_bfloat16* gA = A + (bm + srow) * (long)K + scg * 8;
    const __hip_bfloat16* gB = B + (bn + srow) * (long)K + scg * 8;
    const long rstep = 32 * (long)K;                 // 32 rows per call

    __hip_bfloat16* lA = As + tid * 8;               // call r adds r*32*64 elems
    __hip_bfloat16* lB = Bs + tid * 8;

    floatx4 acc[4][4];
#pragma unroll
    for (int i = 0; i < 4; ++i)
#pragma unroll
        for (int j = 0; j < 4; ++j)
            acc[i][j] = (floatx4){0.f, 0.f, 0.f, 0.f};

    const int fr = lane & 15;            // row/col within 16-tile
    const int fq = lane >> 4;            // k-quad: chunk g = ks*4 + fq

    for (int k0 = 0; k0 < K; k0 += 64) {
#pragma unroll
        for (int r = 0; r < 4; ++r) {
            GLLDS16(gA + k0 + r * rstep, lA + r * 32 * 64);
            GLLDS16(gB + k0 + r * rstep, lB + r * 32 * 64);
        }
        __syncthreads();

#pragma unroll
        for (int ks = 0; ks < 2; ++ks) {
            bf16x8 af[4], bfv[4];
#pragma unroll
            for (int i = 0; i < 4; ++i) {
                const int ra = wr + i * 16 + fr;
                af[i] = *(const bf16x8*)(As + ra * 64 + (((ks * 4 + fq) ^ (ra & 7)) * 8));
            }
#pragma unroll
            for (int j = 0; j < 4; ++j) {
                const int rb = wc + j * 16 + fr;
                bfv[j] = *(const bf16x8*)(Bs + rb * 64 + (((ks * 4 + fq) ^ (rb & 7)) * 8));
            }
#pragma unroll
            for (int i = 0; i < 4; ++i)
#pragma unroll
                for (int j = 0; j < 4; ++j)
                    acc[i][j] = __builtin_amdgcn_mfma_f32_16x16x32_bf16(af[i], bfv[j], acc[i][j], 0, 0, 0);
        }
        __syncthreads();
    }

    // epilogue: C/D layout col=lane&15, row=(lane>>4)*4+reg  [m89/m91]
    const int rq = (lane >> 4) * 4;
#pragma unroll
    for (int j = 0; j < 4; ++j) {
        const long gc = bn + wc + j * 16 + fr;
        const float bj = bias[gc];
#pragma unroll
        for (int i = 0; i < 4; ++i) {
            const long gr = bm + wr + i * 16 + rq;
            float* cp = C + gr * (long)N + gc;
#pragma unroll
            for (int r = 0; r < 4; ++r)
                cp[(long)r * N] = acc[i][j][r] + bj;
        }
    }
}

extern "C" void kernel_launch(void* const* d_in, const int* in_sizes, int n_in,
                              void* d_out, int out_size, void* d_ws, size_t ws_size,
                              hipStream_t stream) {
    const float* x    = (const float*)d_in[0];   // [B,S,K] fp32
    const float* W    = (const float*)d_in[1];   // [N,K]   fp32
    const float* bias = (const float*)d_in[2];   // [N]     fp32
    float* out = (float*)d_out;

    const long long nx = in_sizes[0];
    const long long nw = in_sizes[1];
    const int N = in_sizes[2];
    const int K = (int)(nw / N);
    const int M = (int)(nx / K);

    __hip_bfloat16* xq = (__hip_bfloat16*)d_ws;
    __hip_bfloat16* wq = xq + nx;

    {
        long long tx = nx / 8;
        int blocks = (int)((tx + 255) / 256);
        quant_dq_kernel<<<blocks, 256, 0, stream>>>(x, xq, nx);
    }
    {
        long long tw = nw / 8;
        int blocks = (int)((tw + 255) / 256);
        quant_dq_kernel<<<blocks, 256, 0, stream>>>(W, wq, nw);
    }

    dim3 grid(N / 128, M / 128);
    gemm_bias_kernel<<<grid, 256, 0, stream>>>(xq, wq, bias, out, M, N, K);
}